// Round 18
// baseline (699.494 us; speedup 1.0000x reference)
//
#include <hip/hip_runtime.h>

static inline int cdiv(int a, int b) { return (a + b - 1) / b; }
static inline size_t alignup(size_t x) { return (x + 255) & ~(size_t)255; }

using bf16x8 = __attribute__((ext_vector_type(8))) short;
using f32x4  = __attribute__((ext_vector_type(4))) float;
using u32x4  = __attribute__((ext_vector_type(4))) unsigned int;
using i32x4  = __attribute__((ext_vector_type(4))) int;

__device__ inline unsigned short f2bf(float f) {
    union { float f; unsigned u; } x; x.f = f;
    unsigned r = x.u + 0x7fffu + ((x.u >> 16) & 1u);   // RNE
    return (unsigned short)(r >> 16);
}
__device__ inline float bflo(unsigned u) { union { unsigned u; float f; } x; x.u = u << 16; return x.f; }
__device__ inline float bfhi(unsigned u) { union { unsigned u; float f; } x; x.u = u & 0xffff0000u; return x.f; }
__device__ inline unsigned pack2(float lo, float hi) {
    return (unsigned)f2bf(lo) | ((unsigned)f2bf(hi) << 16);
}

// Bijective XCD-aware swizzle (m204).
__device__ inline int xcd_swz(int bid, int nwg) {
    int q = nwg >> 3, r = nwg & 7;
    int x = bid & 7, p = bid >> 3;
    return (x < r ? x * (q + 1) : r * (q + 1) + (x - r) * q) + p;
}

// packed bf16 atomic add (2 channels per op)
__device__ inline void atomic_pk_bf16(unsigned int* p, unsigned int v) {
    asm volatile("global_atomic_pk_add_bf16 %0, %1, off" :: "v"(p), "v"(v) : "memory");
}

// ---------------------------------------------------------------------------
// weight prep: w2 (27x32x32 f32, [k][cin][cout]) -> B-fragment order bf16.
// nt selects even/odd cout:  cout = 2*(lane&15) + nt.
// ---------------------------------------------------------------------------
__global__ void k_prepw(const float* __restrict__ w2, unsigned short* __restrict__ wf) {
    int e = blockIdx.x * blockDim.x + threadIdx.x;
    if (e >= 27 * 2 * 64 * 8) return;
    int j = e & 7, lane = (e >> 3) & 63, ktile = e >> 9;
    int nt = ktile & 1, k = ktile >> 1;
    int cin = ((lane >> 4) << 3) + j, cout = ((lane & 15) << 1) | nt;
    wf[e] = f2bf(w2[k * 1024 + cin * 32 + cout]);
}

// ---------------------------------------------------------------------------
// scatter: 2 packed-bf16 atomics per point, directly into vfh (M x 4 bf16)
// ---------------------------------------------------------------------------
__global__ __launch_bounds__(256) void k_scatter(const float4* __restrict__ pF,
                                                 const int* __restrict__ idxq,
                                                 unsigned int* __restrict__ vfh, int N) {
    int i = blockIdx.x * blockDim.x + threadIdx.x;
    if (i >= N) return;
    float4 v = pF[i];
    int m = idxq[i];
    unsigned int* p = vfh + (size_t)m * 2;
    atomic_pk_bf16(p,     pack2(v.x, v.y));
    atomic_pk_bf16(p + 1, pack2(v.z, v.w));
}

// vfh[m] /= counts[m] (in place, bf16)
__global__ __launch_bounds__(256) void k_vfnorm(uint2* __restrict__ vfh,
                                                const float* __restrict__ counts, int M) {
    int m = blockIdx.x * blockDim.x + threadIdx.x;
    if (m >= M) return;
    float inv = 1.0f / counts[m];
    uint2 u = vfh[m];
    uint2 o;
    o.x = pack2(bflo(u.x) * inv, bfhi(u.x) * inv);
    o.y = pack2(bflo(u.y) * inv, bfhi(u.y) * inv);
    vfh[m] = o;
}

// ---------------------------------------------------------------------------
// conv1: 4->32.  kmap staged once in LDS (nt loads); bf16 vf gathers;
// nt vectorized h1 stores; BN1 stats fused.  (r13-exact)
// ---------------------------------------------------------------------------
__global__ __launch_bounds__(256) void k_conv1(const uint2* __restrict__ vfh,
                                               const int* __restrict__ kmap,
                                               const float* __restrict__ W,  // 27x4x32
                                               u32x4* __restrict__ h1u, int M,
                                               double* __restrict__ st) {
    __shared__ int skm[256 * 27];
    __shared__ float bs[4][32], bq[4][32];
    int bid = xcd_swz(blockIdx.x, gridDim.x);
    int base = bid * 256;
    int cnt = M - base; if (cnt > 256) cnt = 256;
    int total = cnt * 27;
    const int* kp = kmap + (size_t)base * 27;
    for (int e = threadIdx.x; e < total; e += 256)
        skm[e] = __builtin_nontemporal_load(kp + e);
    __syncthreads();
    int t = threadIdx.x;
    bool act = t < cnt;
    int tc = act ? t : cnt - 1;
    int m = base + tc;
    float4 acc[8];
#pragma unroll
    for (int i = 0; i < 8; ++i) acc[i] = make_float4(0.f, 0.f, 0.f, 0.f);
    const int* km = skm + tc * 27;
#pragma unroll 1
    for (int k = 0; k < 27; ++k) {
        int idx = km[k];
        if (idx < 0) continue;
        uint2 u = vfh[idx];
        float a[4] = {bflo(u.x), bfhi(u.x), bflo(u.y), bfhi(u.y)};
        const float* Wk = W + k * 128;
#pragma unroll
        for (int j = 0; j < 4; ++j) {
#pragma unroll
            for (int c4 = 0; c4 < 8; ++c4) {
                float4 w = *(const float4*)(Wk + j * 32 + c4 * 4);
                acc[c4].x += a[j] * w.x;
                acc[c4].y += a[j] * w.y;
                acc[c4].z += a[j] * w.z;
                acc[c4].w += a[j] * w.w;
            }
        }
    }
    if (!act) {
#pragma unroll
        for (int i = 0; i < 8; ++i) acc[i] = make_float4(0.f, 0.f, 0.f, 0.f);
    }
    if (act) {
        u32x4* o = h1u + (size_t)m * 4;
#pragma unroll
        for (int g = 0; g < 4; ++g) {
            u32x4 pkd;
            pkd[0] = pack2(acc[g * 2].x,     acc[g * 2].y);
            pkd[1] = pack2(acc[g * 2].z,     acc[g * 2].w);
            pkd[2] = pack2(acc[g * 2 + 1].x, acc[g * 2 + 1].y);
            pkd[3] = pack2(acc[g * 2 + 1].z, acc[g * 2 + 1].w);
            __builtin_nontemporal_store(pkd, o + g);
        }
    }
    // ---- fused BN1 stats ----
    int wv = threadIdx.x >> 6, lane = threadIdx.x & 63;
#pragma unroll
    for (int c4 = 0; c4 < 8; ++c4) {
        float vals[4] = {acc[c4].x, acc[c4].y, acc[c4].z, acc[c4].w};
#pragma unroll
        for (int cc = 0; cc < 4; ++cc) {
            float s = vals[cc], q = s * s;
#pragma unroll
            for (int d = 32; d >= 1; d >>= 1) {
                s += __shfl_xor(s, d);
                q += __shfl_xor(q, d);
            }
            if (lane == 0) { bs[wv][c4 * 4 + cc] = s; bq[wv][c4 * 4 + cc] = q; }
        }
    }
    __syncthreads();
    if (threadIdx.x < 32) {
        int c = threadIdx.x;
        float S = bs[0][c] + bs[1][c] + bs[2][c] + bs[3][c];
        float Q = bq[0][c] + bq[1][c] + bq[2][c] + bq[3][c];
        atomicAdd(&st[c], (double)S);
        atomicAdd(&st[32 + c], (double)Q);
    }
}

// ---------------------------------------------------------------------------
// conv2: 32->32 MFMA.  kmap AND weights (54KB) staged in LDS -> weight reads
// come off the TA/VMEM path onto the LDS pipe; A-gathers are the only VMEM.
// nt u32 stores; no post-MFMA barrier.  LDS 62KB -> 2 blocks/CU.
// ---------------------------------------------------------------------------
__global__ __launch_bounds__(256) void k_conv2m(const unsigned short* __restrict__ h1b,
                                                const int* __restrict__ kmap,
                                                const unsigned short* __restrict__ wf,
                                                unsigned short* __restrict__ h2b, int M) {
    __shared__ int skm[64 * 27];                       // 6912 B
    __shared__ unsigned short swf[27 * 2 * 64 * 8];    // 55296 B
    int bid = xcd_swz(blockIdx.x, gridDim.x);
    int vb0 = bid * 64;
    int cnt = M - vb0; if (cnt > 64) cnt = 64;
    int total = cnt * 27;
    const int* kp = kmap + (size_t)vb0 * 27;
    for (int e = threadIdx.x; e < total; e += 256)
        skm[e] = __builtin_nontemporal_load(kp + e);
    {
        const u32x4* src = (const u32x4*)wf;
        u32x4* dst = (u32x4*)swf;
        for (int e = threadIdx.x; e < 3456; e += 256)   // 55296 B / 16
            dst[e] = src[e];
    }
    __syncthreads();
    int lane = threadIdx.x & 63;
    int wv = threadIdx.x >> 6;
    int vbase = vb0 + wv * 16;
    if (vbase >= M) return;
    int col = lane & 15;   // A row (voxel in tile); D col -> channels 2col,2col+1
    int kb = lane >> 4;    // K chunk
    int vloc = wv * 16 + col;
    if (vloc >= cnt) vloc = cnt - 1;
    const int* km = skm + vloc * 27;
    f32x4 acc0 = {0.f, 0.f, 0.f, 0.f};
    f32x4 acc1 = {0.f, 0.f, 0.f, 0.f};
    const bf16x8* wfv = (const bf16x8*)swf;
#pragma unroll 3
    for (int k = 0; k < 27; ++k) {
        int idx = km[k];
        bf16x8 a = {0, 0, 0, 0, 0, 0, 0, 0};
        if (idx >= 0)
            a = *(const bf16x8*)(h1b + (size_t)idx * 32 + kb * 8);
        bf16x8 b0 = wfv[(k * 2 + 0) * 64 + lane];
        bf16x8 b1 = wfv[(k * 2 + 1) * 64 + lane];
        acc0 = __builtin_amdgcn_mfma_f32_16x16x32_bf16(a, b0, acc0, 0, 0, 0);
        acc1 = __builtin_amdgcn_mfma_f32_16x16x32_bf16(a, b1, acc1, 0, 0, 0);
    }
    // D row = kb*4 + r (voxel); one u32 store covers channels 2col, 2col+1
#pragma unroll
    for (int r = 0; r < 4; ++r) {
        int vv = vbase + kb * 4 + r;
        if (vv < M) {
            unsigned int* o = (unsigned int*)(h2b + (size_t)vv * 32) + col;
            __builtin_nontemporal_store(pack2(acc0[r], acc1[r]), o);
        }
    }
}

// ---------------------------------------------------------------------------
// per-channel stats over bf16 rows (32 ch) — separate pass for BN2
// ---------------------------------------------------------------------------
__global__ __launch_bounds__(256) void k_stats_bf(const unsigned short* __restrict__ x,
                                                  int rows, double* __restrict__ st) {
    int c = threadIdx.x & 31;
    int grp = (blockIdx.x * blockDim.x + threadIdx.x) >> 5;
    int ngrp = (gridDim.x * blockDim.x) >> 5;
    float s = 0.f, q = 0.f;
    for (int r = grp; r < rows; r += ngrp) {
        union { unsigned u; float f; } t;
        t.u = ((unsigned)x[(size_t)r * 32 + c]) << 16;
        s += t.f;
        q += t.f * t.f;
    }
    s += __shfl_xor(s, 32);
    q += __shfl_xor(q, 32);
    __shared__ float ls[4][32], lq[4][32];
    int wv = threadIdx.x >> 6, lane = threadIdx.x & 63;
    if (lane < 32) { ls[wv][c] = s; lq[wv][c] = q; }
    __syncthreads();
    if (threadIdx.x < 32) {
        float S = ls[0][c] + ls[1][c] + ls[2][c] + ls[3][c];
        float Q = lq[0][c] + lq[1][c] + lq[2][c] + lq[3][c];
        atomicAdd(&st[c], (double)S);
        atomicAdd(&st[32 + c], (double)Q);
    }
}

__global__ void k_bnparams(const double* __restrict__ st, const float* __restrict__ g,
                           const float* __restrict__ b, double n, float* __restrict__ sb) {
    int c = threadIdx.x;
    if (c >= 32) return;
    double mean = st[c] / n;
    double var = st[32 + c] / n - mean * mean;
    float scale = (float)((double)g[c] / sqrt(var + 1e-5));
    sb[c] = scale;
    sb[32 + c] = b[c] - (float)mean * scale;
}

// BN+ReLU in place on packed bf16 rows. one uint = 2 channels.
__global__ __launch_bounds__(256) void k_bnrelu_bf(unsigned int* __restrict__ x,
                                                   const float* __restrict__ sb, int ng) {
    int i = blockIdx.x * blockDim.x + threadIdx.x;
    int stride = gridDim.x * blockDim.x;
    for (; i < ng; i += stride) {
        int c2 = (i & 15) * 2;
        unsigned int u = x[i];
        float f0 = fmaxf(fmaf(bflo(u), sb[c2],     sb[32 + c2]),     0.f);
        float f1 = fmaxf(fmaf(bfhi(u), sb[c2 + 1], sb[32 + c2 + 1]), 0.f);
        x[i] = pack2(f0, f1);
    }
}

// ---------------------------------------------------------------------------
// devoxelize (bf16 gather, PRE-BN h2b) + inline BN2+ReLU + point transform.
// didx/dwp streamed with NON-TEMPORAL loads (one-touch).
// ---------------------------------------------------------------------------
__device__ inline void devox_pt_bf(int i, const unsigned short* __restrict__ h2b,
                                   const int* __restrict__ didx, const float* __restrict__ dwp,
                                   const float* __restrict__ sb2,
                                   const float* __restrict__ wpt, const float* __restrict__ bpt,
                                   float q[32]) {
    float p[32];
#pragma unroll
    for (int c = 0; c < 32; ++c) p[c] = 0.f;
    const i32x4* di4 = (const i32x4*)(didx + (size_t)i * 8);
    i32x4 dA = __builtin_nontemporal_load(di4);
    i32x4 dB = __builtin_nontemporal_load(di4 + 1);
    const f32x4* dw4 = (const f32x4*)(dwp + (size_t)i * 8);
    f32x4 wA = __builtin_nontemporal_load(dw4);
    f32x4 wB = __builtin_nontemporal_load(dw4 + 1);
    int   di[8] = {dA[0], dA[1], dA[2], dA[3], dB[0], dB[1], dB[2], dB[3]};
    float dr[8] = {wA[0], wA[1], wA[2], wA[3], wB[0], wB[1], wB[2], wB[3]};
#pragma unroll 1
    for (int t = 0; t < 8; ++t) {
        int idx = di[t];
        float w = dr[t];          // exactly 0 when idx < 0
        if (idx < 0) idx = 0;
        const uint4* rp = (const uint4*)(h2b + (size_t)idx * 32);
#pragma unroll
        for (int g = 0; g < 4; ++g) {
            uint4 u = rp[g];
            float h[8] = {bflo(u.x), bfhi(u.x), bflo(u.y), bfhi(u.y),
                          bflo(u.z), bfhi(u.z), bflo(u.w), bfhi(u.w)};
#pragma unroll
            for (int e = 0; e < 8; ++e) {
                int c = g * 8 + e;
                float hv = fmaxf(fmaf(h[e], sb2[c], sb2[32 + c]), 0.f);  // BN2+ReLU
                p[c] += w * hv;
            }
        }
    }
#pragma unroll
    for (int c = 0; c < 32; ++c) q[c] = bpt[c];
    for (int cin = 0; cin < 32; ++cin) {
        float a = p[cin];
        const float* wr = wpt + cin * 32;
#pragma unroll
        for (int c = 0; c < 32; ++c) q[c] += a * wr[c];
    }
}

// pass 1: compute q, store bf16 (plain cached stores -> L3 feeds k_final),
// accumulate BN3 stats
__global__ __launch_bounds__(256) void k_dps(const unsigned short* __restrict__ h2b,
                                             const int* __restrict__ didx,
                                             const float* __restrict__ dwp,
                                             const float* __restrict__ sb2,
                                             const float* __restrict__ wpt,
                                             const float* __restrict__ bpt, int N,
                                             double* __restrict__ st,
                                             unsigned int* __restrict__ qb) {
    float ls[32], lq[32];
#pragma unroll
    for (int c = 0; c < 32; ++c) { ls[c] = 0.f; lq[c] = 0.f; }
    int i = blockIdx.x * blockDim.x + threadIdx.x;
    int stride = gridDim.x * blockDim.x;
    for (; i < N; i += stride) {
        float q[32];
        devox_pt_bf(i, h2b, didx, dwp, sb2, wpt, bpt, q);
        unsigned int* op = qb + (size_t)i * 16;
#pragma unroll
        for (int g = 0; g < 16; ++g) op[g] = pack2(q[2 * g], q[2 * g + 1]);
#pragma unroll
        for (int c = 0; c < 32; ++c) { ls[c] += q[c]; lq[c] += q[c] * q[c]; }
    }
#pragma unroll
    for (int c = 0; c < 32; ++c) {
#pragma unroll
        for (int d = 32; d >= 1; d >>= 1) {
            ls[c] += __shfl_xor(ls[c], d);
            lq[c] += __shfl_xor(lq[c], d);
        }
    }
    __shared__ float bs[4][32], bq[4][32];
    int wv = threadIdx.x >> 6, lane = threadIdx.x & 63;
    if (lane == 0) {
#pragma unroll
        for (int c = 0; c < 32; ++c) { bs[wv][c] = ls[c]; bq[wv][c] = lq[c]; }
    }
    __syncthreads();
    if (threadIdx.x < 32) {
        int c = threadIdx.x;
        float S = bs[0][c] + bs[1][c] + bs[2][c] + bs[3][c];
        float Q = bq[0][c] + bq[1][c] + bq[2][c] + bq[3][c];
        atomicAdd(&st[c], (double)S);
        atomicAdd(&st[32 + c], (double)Q);
    }
}

// pass 2: read q (bf16), BN3+relu, classifier -> out (N x 17 f32)
__global__ __launch_bounds__(256) void k_final(const unsigned int* __restrict__ qb,
                                               const float* __restrict__ sb3,
                                               const float* __restrict__ wcls,
                                               const float* __restrict__ bcls,
                                               float* __restrict__ out, int N) {
    int i = blockIdx.x * blockDim.x + threadIdx.x;
    if (i >= N) return;
    const uint4* rp = (const uint4*)(qb + (size_t)i * 16);
    float f[32];
#pragma unroll
    for (int g = 0; g < 4; ++g) {
        uint4 u = rp[g];
        f[g * 8 + 0] = bflo(u.x); f[g * 8 + 1] = bfhi(u.x);
        f[g * 8 + 2] = bflo(u.y); f[g * 8 + 3] = bfhi(u.y);
        f[g * 8 + 4] = bflo(u.z); f[g * 8 + 5] = bfhi(u.z);
        f[g * 8 + 6] = bflo(u.w); f[g * 8 + 7] = bfhi(u.w);
    }
#pragma unroll
    for (int c = 0; c < 32; ++c)
        f[c] = fmaxf(fmaf(f[c], sb3[c], sb3[32 + c]), 0.f);
    float o[17];
#pragma unroll
    for (int n = 0; n < 17; ++n) o[n] = bcls[n];
#pragma unroll
    for (int c = 0; c < 32; ++c) {
        float fc = f[c];
#pragma unroll
        for (int n = 0; n < 17; ++n) o[n] += fc * wcls[c * 17 + n];
    }
    float* op = out + (size_t)i * 17;
#pragma unroll
    for (int n = 0; n < 17; ++n) op[n] = o[n];
}

// ---------------------------------------------------------------------------
extern "C" void kernel_launch(void* const* d_in, const int* in_sizes, int n_in,
                              void* d_out, int out_size, void* d_ws, size_t ws_size,
                              hipStream_t stream) {
    const float* pF     = (const float*)d_in[0];
    const float* counts = (const float*)d_in[1];
    const float* dwp    = (const float*)d_in[2];
    const float* w1     = (const float*)d_in[3];
    const float* g1     = (const float*)d_in[4];
    const float* b1     = (const float*)d_in[5];
    const float* w2     = (const float*)d_in[6];
    const float* g2     = (const float*)d_in[7];
    const float* b2     = (const float*)d_in[8];
    const float* wpt    = (const float*)d_in[9];
    const float* bpt    = (const float*)d_in[10];
    const float* g3     = (const float*)d_in[11];
    const float* b3     = (const float*)d_in[12];
    const float* wcls   = (const float*)d_in[13];
    const float* bcls   = (const float*)d_in[14];
    const int*   idxq   = (const int*)d_in[15];
    const int*   kmap   = (const int*)d_in[16];
    const int*   didx   = (const int*)d_in[17];

    int N = in_sizes[0] / 4;   // points
    int M = in_sizes[1];       // voxels

    char* ws = (char*)d_ws;
    double* st1 = (double*)(ws + 0);        // 64 doubles each
    double* st2 = (double*)(ws + 512);
    double* st3 = (double*)(ws + 1024);
    float*  sb1 = (float*)(ws + 1536);      // 64 floats each
    float*  sb2 = (float*)(ws + 1792);
    float*  sb3 = (float*)(ws + 2048);
    unsigned short* wf = (unsigned short*)(ws + 2304);         // 55296 B
    size_t off = alignup(57600);
    unsigned int*   vfh  = (unsigned int*)(ws + off);   off = alignup(off + (size_t)M * 8);
    unsigned short* h1b  = (unsigned short*)(ws + off); off = alignup(off + (size_t)M * 64);
    unsigned short* h2b  = (unsigned short*)(ws + off); off = alignup(off + (size_t)M * 64);
    unsigned int*   qb   = (unsigned int*)(ws + off);

    // zero stats + vfh
    hipMemsetAsync(d_ws, 0, 2304, stream);
    hipMemsetAsync(vfh, 0, (size_t)M * 8, stream);

    const int B = 256;
    k_prepw<<<cdiv(27648, B), B, 0, stream>>>(w2, wf);
    k_scatter<<<cdiv(N, B), B, 0, stream>>>((const float4*)pF, idxq, vfh, N);
    k_vfnorm<<<cdiv(M, B), B, 0, stream>>>((uint2*)vfh, counts, M);

    k_conv1<<<cdiv(M, B), B, 0, stream>>>((const uint2*)vfh, kmap, w1, (u32x4*)h1b, M, st1);
    k_bnparams<<<1, 32, 0, stream>>>(st1, g1, b1, (double)M, sb1);
    k_bnrelu_bf<<<2048, B, 0, stream>>>((unsigned int*)h1b, sb1, M * 16);

    k_conv2m<<<cdiv(M, 64), B, 0, stream>>>(h1b, kmap, wf, h2b, M);
    k_stats_bf<<<1024, B, 0, stream>>>(h2b, M, st2);
    k_bnparams<<<1, 32, 0, stream>>>(st2, g2, b2, (double)M, sb2);
    // NOTE: no bnrelu pass on h2b — BN2+ReLU applied inline in k_dps.

    k_dps<<<2048, B, 0, stream>>>(h2b, didx, dwp, sb2, wpt, bpt, N, st3, qb);
    k_bnparams<<<1, 32, 0, stream>>>(st3, g3, b3, (double)N, sb3);
    k_final<<<cdiv(N, B), B, 0, stream>>>(qb, sb3, wcls, bcls, (float*)d_out, N);
}

// Round 19
// 633.903 us; speedup vs baseline: 1.1035x; 1.1035x over previous
//
#include <hip/hip_runtime.h>

static inline int cdiv(int a, int b) { return (a + b - 1) / b; }
static inline size_t alignup(size_t x) { return (x + 255) & ~(size_t)255; }

using bf16x8 = __attribute__((ext_vector_type(8))) short;
using f32x4  = __attribute__((ext_vector_type(4))) float;
using u32x4  = __attribute__((ext_vector_type(4))) unsigned int;
using i32x4  = __attribute__((ext_vector_type(4))) int;

__device__ inline unsigned short f2bf(float f) {
    union { float f; unsigned u; } x; x.f = f;
    unsigned r = x.u + 0x7fffu + ((x.u >> 16) & 1u);   // RNE
    return (unsigned short)(r >> 16);
}
__device__ inline float bflo(unsigned u) { union { unsigned u; float f; } x; x.u = u << 16; return x.f; }
__device__ inline float bfhi(unsigned u) { union { unsigned u; float f; } x; x.u = u & 0xffff0000u; return x.f; }
__device__ inline unsigned pack2(float lo, float hi) {
    return (unsigned)f2bf(lo) | ((unsigned)f2bf(hi) << 16);
}

// Bijective XCD-aware swizzle (m204).
__device__ inline int xcd_swz(int bid, int nwg) {
    int q = nwg >> 3, r = nwg & 7;
    int x = bid & 7, p = bid >> 3;
    return (x < r ? x * (q + 1) : r * (q + 1) + (x - r) * q) + p;
}

// packed bf16 atomic add (2 channels per op)
__device__ inline void atomic_pk_bf16(unsigned int* p, unsigned int v) {
    asm volatile("global_atomic_pk_add_bf16 %0, %1, off" :: "v"(p), "v"(v) : "memory");
}

// ---------------------------------------------------------------------------
// weight prep: w2 (27x32x32 f32, [k][cin][cout]) -> B-fragment order bf16.
// nt selects even/odd cout:  cout = 2*(lane&15) + nt.
// ---------------------------------------------------------------------------
__global__ void k_prepw(const float* __restrict__ w2, unsigned short* __restrict__ wf) {
    int e = blockIdx.x * blockDim.x + threadIdx.x;
    if (e >= 27 * 2 * 64 * 8) return;
    int j = e & 7, lane = (e >> 3) & 63, ktile = e >> 9;
    int nt = ktile & 1, k = ktile >> 1;
    int cin = ((lane >> 4) << 3) + j, cout = ((lane & 15) << 1) | nt;
    wf[e] = f2bf(w2[k * 1024 + cin * 32 + cout]);
}

// ---------------------------------------------------------------------------
// scatter: 2 packed-bf16 atomics per point, directly into vfh (M x 4 bf16)
// ---------------------------------------------------------------------------
__global__ __launch_bounds__(256) void k_scatter(const float4* __restrict__ pF,
                                                 const int* __restrict__ idxq,
                                                 unsigned int* __restrict__ vfh, int N) {
    int i = blockIdx.x * blockDim.x + threadIdx.x;
    if (i >= N) return;
    float4 v = pF[i];
    int m = idxq[i];
    unsigned int* p = vfh + (size_t)m * 2;
    atomic_pk_bf16(p,     pack2(v.x, v.y));
    atomic_pk_bf16(p + 1, pack2(v.z, v.w));
}

// vfh[m] /= counts[m] (in place, bf16)
__global__ __launch_bounds__(256) void k_vfnorm(uint2* __restrict__ vfh,
                                                const float* __restrict__ counts, int M) {
    int m = blockIdx.x * blockDim.x + threadIdx.x;
    if (m >= M) return;
    float inv = 1.0f / counts[m];
    uint2 u = vfh[m];
    uint2 o;
    o.x = pack2(bflo(u.x) * inv, bfhi(u.x) * inv);
    o.y = pack2(bflo(u.y) * inv, bfhi(u.y) * inv);
    vfh[m] = o;
}

// ---------------------------------------------------------------------------
// conv1: 4->32.  kmap staged once in LDS (nt loads); bf16 vf gathers;
// nt vectorized h1 stores; BN1 stats fused.  (r13-exact)
// ---------------------------------------------------------------------------
__global__ __launch_bounds__(256) void k_conv1(const uint2* __restrict__ vfh,
                                               const int* __restrict__ kmap,
                                               const float* __restrict__ W,  // 27x4x32
                                               u32x4* __restrict__ h1u, int M,
                                               double* __restrict__ st) {
    __shared__ int skm[256 * 27];
    __shared__ float bs[4][32], bq[4][32];
    int bid = xcd_swz(blockIdx.x, gridDim.x);
    int base = bid * 256;
    int cnt = M - base; if (cnt > 256) cnt = 256;
    int total = cnt * 27;
    const int* kp = kmap + (size_t)base * 27;
    for (int e = threadIdx.x; e < total; e += 256)
        skm[e] = __builtin_nontemporal_load(kp + e);
    __syncthreads();
    int t = threadIdx.x;
    bool act = t < cnt;
    int tc = act ? t : cnt - 1;
    int m = base + tc;
    float4 acc[8];
#pragma unroll
    for (int i = 0; i < 8; ++i) acc[i] = make_float4(0.f, 0.f, 0.f, 0.f);
    const int* km = skm + tc * 27;
#pragma unroll 1
    for (int k = 0; k < 27; ++k) {
        int idx = km[k];
        if (idx < 0) continue;
        uint2 u = vfh[idx];
        float a[4] = {bflo(u.x), bfhi(u.x), bflo(u.y), bfhi(u.y)};
        const float* Wk = W + k * 128;
#pragma unroll
        for (int j = 0; j < 4; ++j) {
#pragma unroll
            for (int c4 = 0; c4 < 8; ++c4) {
                float4 w = *(const float4*)(Wk + j * 32 + c4 * 4);
                acc[c4].x += a[j] * w.x;
                acc[c4].y += a[j] * w.y;
                acc[c4].z += a[j] * w.z;
                acc[c4].w += a[j] * w.w;
            }
        }
    }
    if (!act) {
#pragma unroll
        for (int i = 0; i < 8; ++i) acc[i] = make_float4(0.f, 0.f, 0.f, 0.f);
    }
    if (act) {
        u32x4* o = h1u + (size_t)m * 4;
#pragma unroll
        for (int g = 0; g < 4; ++g) {
            u32x4 pkd;
            pkd[0] = pack2(acc[g * 2].x,     acc[g * 2].y);
            pkd[1] = pack2(acc[g * 2].z,     acc[g * 2].w);
            pkd[2] = pack2(acc[g * 2 + 1].x, acc[g * 2 + 1].y);
            pkd[3] = pack2(acc[g * 2 + 1].z, acc[g * 2 + 1].w);
            __builtin_nontemporal_store(pkd, o + g);
        }
    }
    // ---- fused BN1 stats ----
    int wv = threadIdx.x >> 6, lane = threadIdx.x & 63;
#pragma unroll
    for (int c4 = 0; c4 < 8; ++c4) {
        float vals[4] = {acc[c4].x, acc[c4].y, acc[c4].z, acc[c4].w};
#pragma unroll
        for (int cc = 0; cc < 4; ++cc) {
            float s = vals[cc], q = s * s;
#pragma unroll
            for (int d = 32; d >= 1; d >>= 1) {
                s += __shfl_xor(s, d);
                q += __shfl_xor(q, d);
            }
            if (lane == 0) { bs[wv][c4 * 4 + cc] = s; bq[wv][c4 * 4 + cc] = q; }
        }
    }
    __syncthreads();
    if (threadIdx.x < 32) {
        int c = threadIdx.x;
        float S = bs[0][c] + bs[1][c] + bs[2][c] + bs[3][c];
        float Q = bq[0][c] + bq[1][c] + bq[2][c] + bq[3][c];
        atomicAdd(&st[c], (double)S);
        atomicAdd(&st[32 + c], (double)Q);
    }
}

// ---------------------------------------------------------------------------
// conv2: 32->32 MFMA.  r13-exact: kmap in LDS; conditional gathers; nt u32
// stores; no post-MFMA barrier.  (best of 5 attempts: 143us, occ 83%)
// ---------------------------------------------------------------------------
__global__ __launch_bounds__(256) void k_conv2m(const unsigned short* __restrict__ h1b,
                                                const int* __restrict__ kmap,
                                                const unsigned short* __restrict__ wf,
                                                unsigned short* __restrict__ h2b, int M) {
    __shared__ int skm[64 * 27];
    int bid = xcd_swz(blockIdx.x, gridDim.x);
    int vb0 = bid * 64;
    int cnt = M - vb0; if (cnt > 64) cnt = 64;
    int total = cnt * 27;
    const int* kp = kmap + (size_t)vb0 * 27;
    for (int e = threadIdx.x; e < total; e += 256)
        skm[e] = __builtin_nontemporal_load(kp + e);
    __syncthreads();
    int lane = threadIdx.x & 63;
    int wv = threadIdx.x >> 6;
    int vbase = vb0 + wv * 16;
    if (vbase >= M) return;
    int col = lane & 15;   // A row (voxel in tile); D col -> channels 2col,2col+1
    int kb = lane >> 4;    // K chunk
    int vloc = wv * 16 + col;
    if (vloc >= cnt) vloc = cnt - 1;
    const int* km = skm + vloc * 27;
    f32x4 acc0 = {0.f, 0.f, 0.f, 0.f};
    f32x4 acc1 = {0.f, 0.f, 0.f, 0.f};
    const bf16x8* wfv = (const bf16x8*)wf;
#pragma unroll 3
    for (int k = 0; k < 27; ++k) {
        int idx = km[k];
        bf16x8 a = {0, 0, 0, 0, 0, 0, 0, 0};
        if (idx >= 0)
            a = *(const bf16x8*)(h1b + (size_t)idx * 32 + kb * 8);
        bf16x8 b0 = wfv[(k * 2 + 0) * 64 + lane];
        bf16x8 b1 = wfv[(k * 2 + 1) * 64 + lane];
        acc0 = __builtin_amdgcn_mfma_f32_16x16x32_bf16(a, b0, acc0, 0, 0, 0);
        acc1 = __builtin_amdgcn_mfma_f32_16x16x32_bf16(a, b1, acc1, 0, 0, 0);
    }
    // D row = kb*4 + r (voxel); one u32 store covers channels 2col, 2col+1
#pragma unroll
    for (int r = 0; r < 4; ++r) {
        int vv = vbase + kb * 4 + r;
        if (vv < M) {
            unsigned int* o = (unsigned int*)(h2b + (size_t)vv * 32) + col;
            __builtin_nontemporal_store(pack2(acc0[r], acc1[r]), o);
        }
    }
}

// ---------------------------------------------------------------------------
// per-channel stats over bf16 rows (32 ch) — separate pass for BN2
// ---------------------------------------------------------------------------
__global__ __launch_bounds__(256) void k_stats_bf(const unsigned short* __restrict__ x,
                                                  int rows, double* __restrict__ st) {
    int c = threadIdx.x & 31;
    int grp = (blockIdx.x * blockDim.x + threadIdx.x) >> 5;
    int ngrp = (gridDim.x * blockDim.x) >> 5;
    float s = 0.f, q = 0.f;
    for (int r = grp; r < rows; r += ngrp) {
        union { unsigned u; float f; } t;
        t.u = ((unsigned)x[(size_t)r * 32 + c]) << 16;
        s += t.f;
        q += t.f * t.f;
    }
    s += __shfl_xor(s, 32);
    q += __shfl_xor(q, 32);
    __shared__ float ls[4][32], lq[4][32];
    int wv = threadIdx.x >> 6, lane = threadIdx.x & 63;
    if (lane < 32) { ls[wv][c] = s; lq[wv][c] = q; }
    __syncthreads();
    if (threadIdx.x < 32) {
        float S = ls[0][c] + ls[1][c] + ls[2][c] + ls[3][c];
        float Q = lq[0][c] + lq[1][c] + lq[2][c] + lq[3][c];
        atomicAdd(&st[c], (double)S);
        atomicAdd(&st[32 + c], (double)Q);
    }
}

__global__ void k_bnparams(const double* __restrict__ st, const float* __restrict__ g,
                           const float* __restrict__ b, double n, float* __restrict__ sb) {
    int c = threadIdx.x;
    if (c >= 32) return;
    double mean = st[c] / n;
    double var = st[32 + c] / n - mean * mean;
    float scale = (float)((double)g[c] / sqrt(var + 1e-5));
    sb[c] = scale;
    sb[32 + c] = b[c] - (float)mean * scale;
}

// BN+ReLU in place on packed bf16 rows. one uint = 2 channels.
__global__ __launch_bounds__(256) void k_bnrelu_bf(unsigned int* __restrict__ x,
                                                   const float* __restrict__ sb, int ng) {
    int i = blockIdx.x * blockDim.x + threadIdx.x;
    int stride = gridDim.x * blockDim.x;
    for (; i < ng; i += stride) {
        int c2 = (i & 15) * 2;
        unsigned int u = x[i];
        float f0 = fmaxf(fmaf(bflo(u), sb[c2],     sb[32 + c2]),     0.f);
        float f1 = fmaxf(fmaf(bfhi(u), sb[c2 + 1], sb[32 + c2 + 1]), 0.f);
        x[i] = pack2(f0, f1);
    }
}

// ---------------------------------------------------------------------------
// devoxelize (bf16 gather, PRE-BN h2b) + inline BN2+ReLU + point transform.
// didx/dwp streamed with NON-TEMPORAL loads (one-touch).
// ---------------------------------------------------------------------------
__device__ inline void devox_pt_bf(int i, const unsigned short* __restrict__ h2b,
                                   const int* __restrict__ didx, const float* __restrict__ dwp,
                                   const float* __restrict__ sb2,
                                   const float* __restrict__ wpt, const float* __restrict__ bpt,
                                   float q[32]) {
    float p[32];
#pragma unroll
    for (int c = 0; c < 32; ++c) p[c] = 0.f;
    const i32x4* di4 = (const i32x4*)(didx + (size_t)i * 8);
    i32x4 dA = __builtin_nontemporal_load(di4);
    i32x4 dB = __builtin_nontemporal_load(di4 + 1);
    const f32x4* dw4 = (const f32x4*)(dwp + (size_t)i * 8);
    f32x4 wA = __builtin_nontemporal_load(dw4);
    f32x4 wB = __builtin_nontemporal_load(dw4 + 1);
    int   di[8] = {dA[0], dA[1], dA[2], dA[3], dB[0], dB[1], dB[2], dB[3]};
    float dr[8] = {wA[0], wA[1], wA[2], wA[3], wB[0], wB[1], wB[2], wB[3]};
#pragma unroll 1
    for (int t = 0; t < 8; ++t) {
        int idx = di[t];
        float w = dr[t];          // exactly 0 when idx < 0
        if (idx < 0) idx = 0;
        const uint4* rp = (const uint4*)(h2b + (size_t)idx * 32);
#pragma unroll
        for (int g = 0; g < 4; ++g) {
            uint4 u = rp[g];
            float h[8] = {bflo(u.x), bfhi(u.x), bflo(u.y), bfhi(u.y),
                          bflo(u.z), bfhi(u.z), bflo(u.w), bfhi(u.w)};
#pragma unroll
            for (int e = 0; e < 8; ++e) {
                int c = g * 8 + e;
                float hv = fmaxf(fmaf(h[e], sb2[c], sb2[32 + c]), 0.f);  // BN2+ReLU
                p[c] += w * hv;
            }
        }
    }
#pragma unroll
    for (int c = 0; c < 32; ++c) q[c] = bpt[c];
    for (int cin = 0; cin < 32; ++cin) {
        float a = p[cin];
        const float* wr = wpt + cin * 32;
#pragma unroll
        for (int c = 0; c < 32; ++c) q[c] += a * wr[c];
    }
}

// pass 1: compute q, store bf16 (plain cached stores -> L3 feeds k_final),
// accumulate BN3 stats
__global__ __launch_bounds__(256) void k_dps(const unsigned short* __restrict__ h2b,
                                             const int* __restrict__ didx,
                                             const float* __restrict__ dwp,
                                             const float* __restrict__ sb2,
                                             const float* __restrict__ wpt,
                                             const float* __restrict__ bpt, int N,
                                             double* __restrict__ st,
                                             unsigned int* __restrict__ qb) {
    float ls[32], lq[32];
#pragma unroll
    for (int c = 0; c < 32; ++c) { ls[c] = 0.f; lq[c] = 0.f; }
    int i = blockIdx.x * blockDim.x + threadIdx.x;
    int stride = gridDim.x * blockDim.x;
    for (; i < N; i += stride) {
        float q[32];
        devox_pt_bf(i, h2b, didx, dwp, sb2, wpt, bpt, q);
        unsigned int* op = qb + (size_t)i * 16;
#pragma unroll
        for (int g = 0; g < 16; ++g) op[g] = pack2(q[2 * g], q[2 * g + 1]);
#pragma unroll
        for (int c = 0; c < 32; ++c) { ls[c] += q[c]; lq[c] += q[c] * q[c]; }
    }
#pragma unroll
    for (int c = 0; c < 32; ++c) {
#pragma unroll
        for (int d = 32; d >= 1; d >>= 1) {
            ls[c] += __shfl_xor(ls[c], d);
            lq[c] += __shfl_xor(lq[c], d);
        }
    }
    __shared__ float bs[4][32], bq[4][32];
    int wv = threadIdx.x >> 6, lane = threadIdx.x & 63;
    if (lane == 0) {
#pragma unroll
        for (int c = 0; c < 32; ++c) { bs[wv][c] = ls[c]; bq[wv][c] = lq[c]; }
    }
    __syncthreads();
    if (threadIdx.x < 32) {
        int c = threadIdx.x;
        float S = bs[0][c] + bs[1][c] + bs[2][c] + bs[3][c];
        float Q = bq[0][c] + bq[1][c] + bq[2][c] + bq[3][c];
        atomicAdd(&st[c], (double)S);
        atomicAdd(&st[32 + c], (double)Q);
    }
}

// pass 2: read q (bf16), BN3+relu, classifier -> out (N x 17 f32)
__global__ __launch_bounds__(256) void k_final(const unsigned int* __restrict__ qb,
                                               const float* __restrict__ sb3,
                                               const float* __restrict__ wcls,
                                               const float* __restrict__ bcls,
                                               float* __restrict__ out, int N) {
    int i = blockIdx.x * blockDim.x + threadIdx.x;
    if (i >= N) return;
    const uint4* rp = (const uint4*)(qb + (size_t)i * 16);
    float f[32];
#pragma unroll
    for (int g = 0; g < 4; ++g) {
        uint4 u = rp[g];
        f[g * 8 + 0] = bflo(u.x); f[g * 8 + 1] = bfhi(u.x);
        f[g * 8 + 2] = bflo(u.y); f[g * 8 + 3] = bfhi(u.y);
        f[g * 8 + 4] = bflo(u.z); f[g * 8 + 5] = bfhi(u.z);
        f[g * 8 + 6] = bflo(u.w); f[g * 8 + 7] = bfhi(u.w);
    }
#pragma unroll
    for (int c = 0; c < 32; ++c)
        f[c] = fmaxf(fmaf(f[c], sb3[c], sb3[32 + c]), 0.f);
    float o[17];
#pragma unroll
    for (int n = 0; n < 17; ++n) o[n] = bcls[n];
#pragma unroll
    for (int c = 0; c < 32; ++c) {
        float fc = f[c];
#pragma unroll
        for (int n = 0; n < 17; ++n) o[n] += fc * wcls[c * 17 + n];
    }
    float* op = out + (size_t)i * 17;
#pragma unroll
    for (int n = 0; n < 17; ++n) op[n] = o[n];
}

// ---------------------------------------------------------------------------
extern "C" void kernel_launch(void* const* d_in, const int* in_sizes, int n_in,
                              void* d_out, int out_size, void* d_ws, size_t ws_size,
                              hipStream_t stream) {
    const float* pF     = (const float*)d_in[0];
    const float* counts = (const float*)d_in[1];
    const float* dwp    = (const float*)d_in[2];
    const float* w1     = (const float*)d_in[3];
    const float* g1     = (const float*)d_in[4];
    const float* b1     = (const float*)d_in[5];
    const float* w2     = (const float*)d_in[6];
    const float* g2     = (const float*)d_in[7];
    const float* b2     = (const float*)d_in[8];
    const float* wpt    = (const float*)d_in[9];
    const float* bpt    = (const float*)d_in[10];
    const float* g3     = (const float*)d_in[11];
    const float* b3     = (const float*)d_in[12];
    const float* wcls   = (const float*)d_in[13];
    const float* bcls   = (const float*)d_in[14];
    const int*   idxq   = (const int*)d_in[15];
    const int*   kmap   = (const int*)d_in[16];
    const int*   didx   = (const int*)d_in[17];

    int N = in_sizes[0] / 4;   // points
    int M = in_sizes[1];       // voxels

    char* ws = (char*)d_ws;
    double* st1 = (double*)(ws + 0);        // 64 doubles each
    double* st2 = (double*)(ws + 512);
    double* st3 = (double*)(ws + 1024);
    float*  sb1 = (float*)(ws + 1536);      // 64 floats each
    float*  sb2 = (float*)(ws + 1792);
    float*  sb3 = (float*)(ws + 2048);
    unsigned short* wf = (unsigned short*)(ws + 2304);         // 55296 B
    size_t off = alignup(57600);
    unsigned int*   vfh  = (unsigned int*)(ws + off);   off = alignup(off + (size_t)M * 8);
    unsigned short* h1b  = (unsigned short*)(ws + off); off = alignup(off + (size_t)M * 64);
    unsigned short* h2b  = (unsigned short*)(ws + off); off = alignup(off + (size_t)M * 64);
    unsigned int*   qb   = (unsigned int*)(ws + off);

    // zero stats + vfh
    hipMemsetAsync(d_ws, 0, 2304, stream);
    hipMemsetAsync(vfh, 0, (size_t)M * 8, stream);

    const int B = 256;
    k_prepw<<<cdiv(27648, B), B, 0, stream>>>(w2, wf);
    k_scatter<<<cdiv(N, B), B, 0, stream>>>((const float4*)pF, idxq, vfh, N);
    k_vfnorm<<<cdiv(M, B), B, 0, stream>>>((uint2*)vfh, counts, M);

    k_conv1<<<cdiv(M, B), B, 0, stream>>>((const uint2*)vfh, kmap, w1, (u32x4*)h1b, M, st1);
    k_bnparams<<<1, 32, 0, stream>>>(st1, g1, b1, (double)M, sb1);
    k_bnrelu_bf<<<2048, B, 0, stream>>>((unsigned int*)h1b, sb1, M * 16);

    k_conv2m<<<cdiv(M, 64), B, 0, stream>>>(h1b, kmap, wf, h2b, M);
    k_stats_bf<<<1024, B, 0, stream>>>(h2b, M, st2);
    k_bnparams<<<1, 32, 0, stream>>>(st2, g2, b2, (double)M, sb2);
    // NOTE: no bnrelu pass on h2b — BN2+ReLU applied inline in k_dps.

    k_dps<<<2048, B, 0, stream>>>(h2b, didx, dwp, sb2, wpt, bpt, N, st3, qb);
    k_bnparams<<<1, 32, 0, stream>>>(st3, g3, b3, (double)N, sb3);
    k_final<<<cdiv(N, B), B, 0, stream>>>(qb, sb3, wcls, bcls, (float*)d_out, N);
}

// Round 21
// 603.650 us; speedup vs baseline: 1.1588x; 1.0501x over previous
//
#include <hip/hip_runtime.h>

static inline int cdiv(int a, int b) { return (a + b - 1) / b; }
static inline size_t alignup(size_t x) { return (x + 255) & ~(size_t)255; }

using bf16x8 = __attribute__((ext_vector_type(8))) short;
using f32x4  = __attribute__((ext_vector_type(4))) float;
using u32x4  = __attribute__((ext_vector_type(4))) unsigned int;
using i32x4  = __attribute__((ext_vector_type(4))) int;

__device__ inline unsigned short f2bf(float f) {
    union { float f; unsigned u; } x; x.f = f;
    unsigned r = x.u + 0x7fffu + ((x.u >> 16) & 1u);   // RNE
    return (unsigned short)(r >> 16);
}
__device__ inline float bflo(unsigned u) { union { unsigned u; float f; } x; x.u = u << 16; return x.f; }
__device__ inline float bfhi(unsigned u) { union { unsigned u; float f; } x; x.u = u & 0xffff0000u; return x.f; }
__device__ inline unsigned pack2(float lo, float hi) {
    return (unsigned)f2bf(lo) | ((unsigned)f2bf(hi) << 16);
}

// Bijective XCD-aware swizzle (m204).
__device__ inline int xcd_swz(int bid, int nwg) {
    int q = nwg >> 3, r = nwg & 7;
    int x = bid & 7, p = bid >> 3;
    return (x < r ? x * (q + 1) : r * (q + 1) + (x - r) * q) + p;
}

// packed bf16 atomic add (2 channels per op)
__device__ inline void atomic_pk_bf16(unsigned int* p, unsigned int v) {
    asm volatile("global_atomic_pk_add_bf16 %0, %1, off" :: "v"(p), "v"(v) : "memory");
}

// ---------------------------------------------------------------------------
// weight prep: w2 (27x32x32 f32, [k][cin][cout]) -> B-fragment order bf16.
// nt selects even/odd cout:  cout = 2*(lane&15) + nt.
// ---------------------------------------------------------------------------
__global__ void k_prepw(const float* __restrict__ w2, unsigned short* __restrict__ wf) {
    int e = blockIdx.x * blockDim.x + threadIdx.x;
    if (e >= 27 * 2 * 64 * 8) return;
    int j = e & 7, lane = (e >> 3) & 63, ktile = e >> 9;
    int nt = ktile & 1, k = ktile >> 1;
    int cin = ((lane >> 4) << 3) + j, cout = ((lane & 15) << 1) | nt;
    wf[e] = f2bf(w2[k * 1024 + cin * 32 + cout]);
}

// ---------------------------------------------------------------------------
// scatter: 2 packed-bf16 atomics per point, directly into vfh (M x 4 bf16)
// ---------------------------------------------------------------------------
__global__ __launch_bounds__(256) void k_scatter(const float4* __restrict__ pF,
                                                 const int* __restrict__ idxq,
                                                 unsigned int* __restrict__ vfh, int N) {
    int i = blockIdx.x * blockDim.x + threadIdx.x;
    if (i >= N) return;
    float4 v = pF[i];
    int m = idxq[i];
    unsigned int* p = vfh + (size_t)m * 2;
    atomic_pk_bf16(p,     pack2(v.x, v.y));
    atomic_pk_bf16(p + 1, pack2(v.z, v.w));
}

// vfh[m] /= counts[m] (in place, bf16)
__global__ __launch_bounds__(256) void k_vfnorm(uint2* __restrict__ vfh,
                                                const float* __restrict__ counts, int M) {
    int m = blockIdx.x * blockDim.x + threadIdx.x;
    if (m >= M) return;
    float inv = 1.0f / counts[m];
    uint2 u = vfh[m];
    uint2 o;
    o.x = pack2(bflo(u.x) * inv, bfhi(u.x) * inv);
    o.y = pack2(bflo(u.y) * inv, bfhi(u.y) * inv);
    vfh[m] = o;
}

// ---------------------------------------------------------------------------
// conv1: 4->32.  kmap staged once in LDS (nt loads); bf16 vf gathers;
// nt vectorized h1 stores; BN1 stats fused.  (r13-exact)
// ---------------------------------------------------------------------------
__global__ __launch_bounds__(256) void k_conv1(const uint2* __restrict__ vfh,
                                               const int* __restrict__ kmap,
                                               const float* __restrict__ W,  // 27x4x32
                                               u32x4* __restrict__ h1u, int M,
                                               double* __restrict__ st) {
    __shared__ int skm[256 * 27];
    __shared__ float bs[4][32], bq[4][32];
    int bid = xcd_swz(blockIdx.x, gridDim.x);
    int base = bid * 256;
    int cnt = M - base; if (cnt > 256) cnt = 256;
    int total = cnt * 27;
    const int* kp = kmap + (size_t)base * 27;
    for (int e = threadIdx.x; e < total; e += 256)
        skm[e] = __builtin_nontemporal_load(kp + e);
    __syncthreads();
    int t = threadIdx.x;
    bool act = t < cnt;
    int tc = act ? t : cnt - 1;
    int m = base + tc;
    float4 acc[8];
#pragma unroll
    for (int i = 0; i < 8; ++i) acc[i] = make_float4(0.f, 0.f, 0.f, 0.f);
    const int* km = skm + tc * 27;
#pragma unroll 1
    for (int k = 0; k < 27; ++k) {
        int idx = km[k];
        if (idx < 0) continue;
        uint2 u = vfh[idx];
        float a[4] = {bflo(u.x), bfhi(u.x), bflo(u.y), bfhi(u.y)};
        const float* Wk = W + k * 128;
#pragma unroll
        for (int j = 0; j < 4; ++j) {
#pragma unroll
            for (int c4 = 0; c4 < 8; ++c4) {
                float4 w = *(const float4*)(Wk + j * 32 + c4 * 4);
                acc[c4].x += a[j] * w.x;
                acc[c4].y += a[j] * w.y;
                acc[c4].z += a[j] * w.z;
                acc[c4].w += a[j] * w.w;
            }
        }
    }
    if (!act) {
#pragma unroll
        for (int i = 0; i < 8; ++i) acc[i] = make_float4(0.f, 0.f, 0.f, 0.f);
    }
    if (act) {
        u32x4* o = h1u + (size_t)m * 4;
#pragma unroll
        for (int g = 0; g < 4; ++g) {
            u32x4 pkd;
            pkd[0] = pack2(acc[g * 2].x,     acc[g * 2].y);
            pkd[1] = pack2(acc[g * 2].z,     acc[g * 2].w);
            pkd[2] = pack2(acc[g * 2 + 1].x, acc[g * 2 + 1].y);
            pkd[3] = pack2(acc[g * 2 + 1].z, acc[g * 2 + 1].w);
            __builtin_nontemporal_store(pkd, o + g);
        }
    }
    // ---- fused BN1 stats ----
    int wv = threadIdx.x >> 6, lane = threadIdx.x & 63;
#pragma unroll
    for (int c4 = 0; c4 < 8; ++c4) {
        float vals[4] = {acc[c4].x, acc[c4].y, acc[c4].z, acc[c4].w};
#pragma unroll
        for (int cc = 0; cc < 4; ++cc) {
            float s = vals[cc], q = s * s;
#pragma unroll
            for (int d = 32; d >= 1; d >>= 1) {
                s += __shfl_xor(s, d);
                q += __shfl_xor(q, d);
            }
            if (lane == 0) { bs[wv][c4 * 4 + cc] = s; bq[wv][c4 * 4 + cc] = q; }
        }
    }
    __syncthreads();
    if (threadIdx.x < 32) {
        int c = threadIdx.x;
        float S = bs[0][c] + bs[1][c] + bs[2][c] + bs[3][c];
        float Q = bq[0][c] + bq[1][c] + bq[2][c] + bq[3][c];
        atomicAdd(&st[c], (double)S);
        atomicAdd(&st[32 + c], (double)Q);
    }
}

// ---------------------------------------------------------------------------
// conv2: 32->32 MFMA.  DUAL-TILE: each wave computes TWO 16-voxel tiles that
// SHARE the weight fragment loads -> per-voxel line transactions drop 81->54.
// kmap in LDS; conditional gathers; nt u32 stores; no post-MFMA barrier.
// ---------------------------------------------------------------------------
__global__ __launch_bounds__(256) void k_conv2m(const unsigned short* __restrict__ h1b,
                                                const int* __restrict__ kmap,
                                                const unsigned short* __restrict__ wf,
                                                unsigned short* __restrict__ h2b, int M) {
    __shared__ int skm[128 * 27];                     // 13824 B
    int bid = xcd_swz(blockIdx.x, gridDim.x);
    int vb0 = bid * 128;
    int cnt = M - vb0; if (cnt > 128) cnt = 128;
    int total = cnt * 27;
    const int* kp = kmap + (size_t)vb0 * 27;
    for (int e = threadIdx.x; e < total; e += 256)
        skm[e] = __builtin_nontemporal_load(kp + e);
    __syncthreads();
    int lane = threadIdx.x & 63;
    int wv = threadIdx.x >> 6;
    int vbase0 = vb0 + wv * 32;        // tile0: rows vbase0..vbase0+15
    if (vbase0 >= M) return;
    int vbase1 = vbase0 + 16;          // tile1: rows vbase1..vbase1+15
    int col = lane & 15;   // A row (voxel in tile); D col -> channels 2col,2col+1
    int kb = lane >> 4;    // K chunk
    int vloc0 = wv * 32 + col;      if (vloc0 >= cnt) vloc0 = cnt - 1;
    int vloc1 = wv * 32 + 16 + col; if (vloc1 >= cnt) vloc1 = cnt - 1;
    const int* km0 = skm + vloc0 * 27;
    const int* km1 = skm + vloc1 * 27;
    f32x4 acc00 = {0.f, 0.f, 0.f, 0.f};
    f32x4 acc01 = {0.f, 0.f, 0.f, 0.f};
    f32x4 acc10 = {0.f, 0.f, 0.f, 0.f};
    f32x4 acc11 = {0.f, 0.f, 0.f, 0.f};
    const bf16x8* wfv = (const bf16x8*)wf;
#pragma unroll 3
    for (int k = 0; k < 27; ++k) {
        int idx0 = km0[k];
        int idx1 = km1[k];
        bf16x8 a0 = {0, 0, 0, 0, 0, 0, 0, 0};
        bf16x8 a1 = {0, 0, 0, 0, 0, 0, 0, 0};
        if (idx0 >= 0)
            a0 = *(const bf16x8*)(h1b + (size_t)idx0 * 32 + kb * 8);
        if (idx1 >= 0)
            a1 = *(const bf16x8*)(h1b + (size_t)idx1 * 32 + kb * 8);
        bf16x8 b0 = wfv[(k * 2 + 0) * 64 + lane];   // shared by both tiles
        bf16x8 b1 = wfv[(k * 2 + 1) * 64 + lane];
        acc00 = __builtin_amdgcn_mfma_f32_16x16x32_bf16(a0, b0, acc00, 0, 0, 0);
        acc01 = __builtin_amdgcn_mfma_f32_16x16x32_bf16(a0, b1, acc01, 0, 0, 0);
        acc10 = __builtin_amdgcn_mfma_f32_16x16x32_bf16(a1, b0, acc10, 0, 0, 0);
        acc11 = __builtin_amdgcn_mfma_f32_16x16x32_bf16(a1, b1, acc11, 0, 0, 0);
    }
    // D row = kb*4 + r (voxel); one u32 store covers channels 2col, 2col+1
#pragma unroll
    for (int r = 0; r < 4; ++r) {
        int vv = vbase0 + kb * 4 + r;
        if (vv < M) {
            unsigned int* o = (unsigned int*)(h2b + (size_t)vv * 32) + col;
            __builtin_nontemporal_store(pack2(acc00[r], acc01[r]), o);
        }
    }
#pragma unroll
    for (int r = 0; r < 4; ++r) {
        int vv = vbase1 + kb * 4 + r;
        if (vv < M) {
            unsigned int* o = (unsigned int*)(h2b + (size_t)vv * 32) + col;
            __builtin_nontemporal_store(pack2(acc10[r], acc11[r]), o);
        }
    }
}

// ---------------------------------------------------------------------------
// per-channel stats over bf16 rows (32 ch) — separate pass for BN2
// ---------------------------------------------------------------------------
__global__ __launch_bounds__(256) void k_stats_bf(const unsigned short* __restrict__ x,
                                                  int rows, double* __restrict__ st) {
    int c = threadIdx.x & 31;
    int grp = (blockIdx.x * blockDim.x + threadIdx.x) >> 5;
    int ngrp = (gridDim.x * blockDim.x) >> 5;
    float s = 0.f, q = 0.f;
    for (int r = grp; r < rows; r += ngrp) {
        union { unsigned u; float f; } t;
        t.u = ((unsigned)x[(size_t)r * 32 + c]) << 16;
        s += t.f;
        q += t.f * t.f;
    }
    s += __shfl_xor(s, 32);
    q += __shfl_xor(q, 32);
    __shared__ float ls[4][32], lq[4][32];
    int wv = threadIdx.x >> 6, lane = threadIdx.x & 63;
    if (lane < 32) { ls[wv][c] = s; lq[wv][c] = q; }
    __syncthreads();
    if (threadIdx.x < 32) {
        float S = ls[0][c] + ls[1][c] + ls[2][c] + ls[3][c];
        float Q = lq[0][c] + lq[1][c] + lq[2][c] + lq[3][c];
        atomicAdd(&st[c], (double)S);
        atomicAdd(&st[32 + c], (double)Q);
    }
}

__global__ void k_bnparams(const double* __restrict__ st, const float* __restrict__ g,
                           const float* __restrict__ b, double n, float* __restrict__ sb) {
    int c = threadIdx.x;
    if (c >= 32) return;
    double mean = st[c] / n;
    double var = st[32 + c] / n - mean * mean;
    float scale = (float)((double)g[c] / sqrt(var + 1e-5));
    sb[c] = scale;
    sb[32 + c] = b[c] - (float)mean * scale;
}

// BN+ReLU in place on packed bf16 rows. one uint = 2 channels.
__global__ __launch_bounds__(256) void k_bnrelu_bf(unsigned int* __restrict__ x,
                                                   const float* __restrict__ sb, int ng) {
    int i = blockIdx.x * blockDim.x + threadIdx.x;
    int stride = gridDim.x * blockDim.x;
    for (; i < ng; i += stride) {
        int c2 = (i & 15) * 2;
        unsigned int u = x[i];
        float f0 = fmaxf(fmaf(bflo(u), sb[c2],     sb[32 + c2]),     0.f);
        float f1 = fmaxf(fmaf(bfhi(u), sb[c2 + 1], sb[32 + c2 + 1]), 0.f);
        x[i] = pack2(f0, f1);
    }
}

// ---------------------------------------------------------------------------
// devoxelize (bf16 gather, PRE-BN h2b) + inline BN2+ReLU + point transform.
// didx/dwp streamed with NON-TEMPORAL loads (one-touch).
// ---------------------------------------------------------------------------
__device__ inline void devox_pt_bf(int i, const unsigned short* __restrict__ h2b,
                                   const int* __restrict__ didx, const float* __restrict__ dwp,
                                   const float* __restrict__ sb2,
                                   const float* __restrict__ wpt, const float* __restrict__ bpt,
                                   float q[32]) {
    float p[32];
#pragma unroll
    for (int c = 0; c < 32; ++c) p[c] = 0.f;
    const i32x4* di4 = (const i32x4*)(didx + (size_t)i * 8);
    i32x4 dA = __builtin_nontemporal_load(di4);
    i32x4 dB = __builtin_nontemporal_load(di4 + 1);
    const f32x4* dw4 = (const f32x4*)(dwp + (size_t)i * 8);
    f32x4 wA = __builtin_nontemporal_load(dw4);
    f32x4 wB = __builtin_nontemporal_load(dw4 + 1);
    int   di[8] = {dA[0], dA[1], dA[2], dA[3], dB[0], dB[1], dB[2], dB[3]};
    float dr[8] = {wA[0], wA[1], wA[2], wA[3], wB[0], wB[1], wB[2], wB[3]};
#pragma unroll 1
    for (int t = 0; t < 8; ++t) {
        int idx = di[t];
        float w = dr[t];          // exactly 0 when idx < 0
        if (idx < 0) idx = 0;
        const uint4* rp = (const uint4*)(h2b + (size_t)idx * 32);
#pragma unroll
        for (int g = 0; g < 4; ++g) {
            uint4 u = rp[g];
            float h[8] = {bflo(u.x), bfhi(u.x), bflo(u.y), bfhi(u.y),
                          bflo(u.z), bfhi(u.z), bflo(u.w), bfhi(u.w)};
#pragma unroll
            for (int e = 0; e < 8; ++e) {
                int c = g * 8 + e;
                float hv = fmaxf(fmaf(h[e], sb2[c], sb2[32 + c]), 0.f);  // BN2+ReLU
                p[c] += w * hv;
            }
        }
    }
#pragma unroll
    for (int c = 0; c < 32; ++c) q[c] = bpt[c];
    for (int cin = 0; cin < 32; ++cin) {
        float a = p[cin];
        const float* wr = wpt + cin * 32;
#pragma unroll
        for (int c = 0; c < 32; ++c) q[c] += a * wr[c];
    }
}

// pass 1: compute q, store bf16 (plain cached stores -> L3 feeds k_final),
// accumulate BN3 stats
__global__ __launch_bounds__(256) void k_dps(const unsigned short* __restrict__ h2b,
                                             const int* __restrict__ didx,
                                             const float* __restrict__ dwp,
                                             const float* __restrict__ sb2,
                                             const float* __restrict__ wpt,
                                             const float* __restrict__ bpt, int N,
                                             double* __restrict__ st,
                                             unsigned int* __restrict__ qb) {
    float ls[32], lq[32];
#pragma unroll
    for (int c = 0; c < 32; ++c) { ls[c] = 0.f; lq[c] = 0.f; }
    int i = blockIdx.x * blockDim.x + threadIdx.x;
    int stride = gridDim.x * blockDim.x;
    for (; i < N; i += stride) {
        float q[32];
        devox_pt_bf(i, h2b, didx, dwp, sb2, wpt, bpt, q);
        unsigned int* op = qb + (size_t)i * 16;
#pragma unroll
        for (int g = 0; g < 16; ++g) op[g] = pack2(q[2 * g], q[2 * g + 1]);
#pragma unroll
        for (int c = 0; c < 32; ++c) { ls[c] += q[c]; lq[c] += q[c] * q[c]; }
    }
#pragma unroll
    for (int c = 0; c < 32; ++c) {
#pragma unroll
        for (int d = 32; d >= 1; d >>= 1) {
            ls[c] += __shfl_xor(ls[c], d);
            lq[c] += __shfl_xor(lq[c], d);
        }
    }
    __shared__ float bs[4][32], bq[4][32];
    int wv = threadIdx.x >> 6, lane = threadIdx.x & 63;
    if (lane == 0) {
#pragma unroll
        for (int c = 0; c < 32; ++c) { bs[wv][c] = ls[c]; bq[wv][c] = lq[c]; }
    }
    __syncthreads();
    if (threadIdx.x < 32) {
        int c = threadIdx.x;
        float S = bs[0][c] + bs[1][c] + bs[2][c] + bs[3][c];
        float Q = bq[0][c] + bq[1][c] + bq[2][c] + bq[3][c];
        atomicAdd(&st[c], (double)S);
        atomicAdd(&st[32 + c], (double)Q);
    }
}

// pass 2: read q (bf16), BN3+relu, classifier -> out (N x 17 f32)
__global__ __launch_bounds__(256) void k_final(const unsigned int* __restrict__ qb,
                                               const float* __restrict__ sb3,
                                               const float* __restrict__ wcls,
                                               const float* __restrict__ bcls,
                                               float* __restrict__ out, int N) {
    int i = blockIdx.x * blockDim.x + threadIdx.x;
    if (i >= N) return;
    const uint4* rp = (const uint4*)(qb + (size_t)i * 16);
    float f[32];
#pragma unroll
    for (int g = 0; g < 4; ++g) {
        uint4 u = rp[g];
        f[g * 8 + 0] = bflo(u.x); f[g * 8 + 1] = bfhi(u.x);
        f[g * 8 + 2] = bflo(u.y); f[g * 8 + 3] = bfhi(u.y);
        f[g * 8 + 4] = bflo(u.z); f[g * 8 + 5] = bfhi(u.z);
        f[g * 8 + 6] = bflo(u.w); f[g * 8 + 7] = bfhi(u.w);
    }
#pragma unroll
    for (int c = 0; c < 32; ++c)
        f[c] = fmaxf(fmaf(f[c], sb3[c], sb3[32 + c]), 0.f);
    float o[17];
#pragma unroll
    for (int n = 0; n < 17; ++n) o[n] = bcls[n];
#pragma unroll
    for (int c = 0; c < 32; ++c) {
        float fc = f[c];
#pragma unroll
        for (int n = 0; n < 17; ++n) o[n] += fc * wcls[c * 17 + n];
    }
    float* op = out + (size_t)i * 17;
#pragma unroll
    for (int n = 0; n < 17; ++n) op[n] = o[n];
}

// ---------------------------------------------------------------------------
extern "C" void kernel_launch(void* const* d_in, const int* in_sizes, int n_in,
                              void* d_out, int out_size, void* d_ws, size_t ws_size,
                              hipStream_t stream) {
    const float* pF     = (const float*)d_in[0];
    const float* counts = (const float*)d_in[1];
    const float* dwp    = (const float*)d_in[2];
    const float* w1     = (const float*)d_in[3];
    const float* g1     = (const float*)d_in[4];
    const float* b1     = (const float*)d_in[5];
    const float* w2     = (const float*)d_in[6];
    const float* g2     = (const float*)d_in[7];
    const float* b2     = (const float*)d_in[8];
    const float* wpt    = (const float*)d_in[9];
    const float* bpt    = (const float*)d_in[10];
    const float* g3     = (const float*)d_in[11];
    const float* b3     = (const float*)d_in[12];
    const float* wcls   = (const float*)d_in[13];
    const float* bcls   = (const float*)d_in[14];
    const int*   idxq   = (const int*)d_in[15];
    const int*   kmap   = (const int*)d_in[16];
    const int*   didx   = (const int*)d_in[17];

    int N = in_sizes[0] / 4;   // points
    int M = in_sizes[1];       // voxels

    char* ws = (char*)d_ws;
    double* st1 = (double*)(ws + 0);        // 64 doubles each
    double* st2 = (double*)(ws + 512);
    double* st3 = (double*)(ws + 1024);
    float*  sb1 = (float*)(ws + 1536);      // 64 floats each
    float*  sb2 = (float*)(ws + 1792);
    float*  sb3 = (float*)(ws + 2048);
    unsigned short* wf = (unsigned short*)(ws + 2304);         // 55296 B
    size_t off = alignup(57600);
    unsigned int*   vfh  = (unsigned int*)(ws + off);   off = alignup(off + (size_t)M * 8);
    unsigned short* h1b  = (unsigned short*)(ws + off); off = alignup(off + (size_t)M * 64);
    unsigned short* h2b  = (unsigned short*)(ws + off); off = alignup(off + (size_t)M * 64);
    unsigned int*   qb   = (unsigned int*)(ws + off);

    // zero stats + vfh
    hipMemsetAsync(d_ws, 0, 2304, stream);
    hipMemsetAsync(vfh, 0, (size_t)M * 8, stream);

    const int B = 256;
    k_prepw<<<cdiv(27648, B), B, 0, stream>>>(w2, wf);
    k_scatter<<<cdiv(N, B), B, 0, stream>>>((const float4*)pF, idxq, vfh, N);
    k_vfnorm<<<cdiv(M, B), B, 0, stream>>>((uint2*)vfh, counts, M);

    k_conv1<<<cdiv(M, B), B, 0, stream>>>((const uint2*)vfh, kmap, w1, (u32x4*)h1b, M, st1);
    k_bnparams<<<1, 32, 0, stream>>>(st1, g1, b1, (double)M, sb1);
    k_bnrelu_bf<<<2048, B, 0, stream>>>((unsigned int*)h1b, sb1, M * 16);

    k_conv2m<<<cdiv(M, 128), B, 0, stream>>>(h1b, kmap, wf, h2b, M);
    k_stats_bf<<<1024, B, 0, stream>>>(h2b, M, st2);
    k_bnparams<<<1, 32, 0, stream>>>(st2, g2, b2, (double)M, sb2);
    // NOTE: no bnrelu pass on h2b — BN2+ReLU applied inline in k_dps.

    k_dps<<<2048, B, 0, stream>>>(h2b, didx, dwp, sb2, wpt, bpt, N, st3, qb);
    k_bnparams<<<1, 32, 0, stream>>>(st3, g3, b3, (double)N, sb3);
    k_final<<<cdiv(N, B), B, 0, stream>>>(qb, sb3, wcls, bcls, (float*)d_out, N);
}